// Round 2
// 1127.537 us; speedup vs baseline: 1.2406x; 1.2406x over previous
//
#include <hip/hip_runtime.h>
#include <stdint.h>

// Int4Linear: out[M,N] = x[M,K] @ dequant(W)[N,K]^T + bias[N]
// M=8192, N=11008, K=4096.
//
// R4: pass 1 unchanged (x->bf16, W->bf16 into d_ws). Pass 2: 256x256 BK=64
// GEMM, 512 thr / 8 waves (2x4), 128 KiB double-buffered LDS, swizzled
// global_load_lds w=16, 4 phases per K-tile.
// R3 bug fixed: reads of a tile are wave-dependent (wm=1 waves read A rows
// 128+ at P0), so the WHOLE K-tile must be resident before P0. Counted
// vmcnt is kept by pre-issuing tile t+2's first 2 chunks (into buf[cur],
// legal after P2-end barrier) so the P3 wait is vmcnt(2) = exactly tile
// t+1's 8 loads drained, t+2's 2 in flight.

#define M_TOTAL 8192
#define N_TOTAL 11008
#define K_TOTAL 4096
#define KP      2048
#define NG      32

// fused-fallback geometry (R1 kernel)
#define BM 128
#define BN 128
#define BK 32
#define MT (M_TOTAL / BM)   // 64
#define NT (N_TOTAL / BN)   // 86

// 256x256 GEMM geometry
#define BM2 256
#define BN2 256
#define BK2 64
#define MT2 (M_TOTAL / BM2)   // 32
#define NT2 (N_TOTAL / BN2)   // 43
#define NKT (K_TOTAL / BK2)   // 64

typedef __bf16 bf16x8 __attribute__((ext_vector_type(8)));
typedef float  f32x4  __attribute__((ext_vector_type(4)));

__device__ __forceinline__ unsigned pack2_bf16(float f0, float f1) {
    unsigned b0 = __float_as_uint(f0);
    unsigned b1 = __float_as_uint(f1);
    return ((b0 + 0x8000u) >> 16) | ((b1 + 0x8000u) & 0xFFFF0000u);
}

// ---------------- pass 1a: x fp32 -> bf16 ----------------
__global__ __launch_bounds__(256)
void convert_x(const float* __restrict__ x, unsigned short* __restrict__ xb)
{
    size_t i = ((size_t)blockIdx.x * 256 + threadIdx.x) * 8;
    float4 a0 = *(const float4*)(x + i);
    float4 a1 = *(const float4*)(x + i + 4);
    uint4 o;
    o.x = pack2_bf16(a0.x, a0.y);
    o.y = pack2_bf16(a0.z, a0.w);
    o.z = pack2_bf16(a1.x, a1.y);
    o.w = pack2_bf16(a1.z, a1.w);
    *(uint4*)(xb + i) = o;
}

// ---------------- pass 1b: W int4 -> bf16 [N,K] row-major ----------------
__global__ __launch_bounds__(256)
void dequant_w(const int* __restrict__ wp, const float* __restrict__ scale,
               const float* __restrict__ zp, unsigned short* __restrict__ wb)
{
    size_t tid = (size_t)blockIdx.x * 256 + threadIdx.x;
    size_t pi = tid * 4;
    int row = (int)(pi >> 11);
    int p0  = (int)(pi & (KP - 1));
    int g   = p0 >> 6;
    float s = scale[row * NG + g];
    float c = -zp[row * NG + g] * s;
    int4 v = *(const int4*)(wp + pi);
    int bv[4] = {v.x, v.y, v.z, v.w};
    unsigned ou[4];
    #pragma unroll
    for (int j = 0; j < 4; ++j) {
        unsigned u = (unsigned)bv[j];
        float fh = (float)((u >> 4) & 15u) * s + c;
        float fl = (float)( u       & 15u) * s + c;
        ou[j] = pack2_bf16(fh, fl);
    }
    *(uint4*)(wb + 2 * pi) = make_uint4(ou[0], ou[1], ou[2], ou[3]);
}

// ---------------- global -> LDS direct (width 16) ----------------
__device__ __forceinline__ void load_lds16(const void* g, void* l) {
    __builtin_amdgcn_global_load_lds(
        (const __attribute__((address_space(1))) unsigned int*)(uintptr_t)g,
        (__attribute__((address_space(3))) unsigned int*)(uintptr_t)l,
        16, 0, 0);
}

// ---------------- pass 2: 256x256 4-phase bf16 GEMM ----------------
// LDS tile: [256 rows][64 k] bf16, 128 B/row. 16B slot c of row r holds
// global slot c ^ (r&7) (pre-swizzled global source, linear LDS dest;
// ds_read applies the same XOR). ds_read_b128 conflict: 16-way -> 2-way.

__global__ __launch_bounds__(512, 2)
void gemm256(const unsigned short* __restrict__ A,   // [M,K] bf16
             const unsigned short* __restrict__ B,   // [N,K] bf16
             const float* __restrict__ bias,
             float* __restrict__ out)
{
    __shared__ unsigned short As[2 * BM2 * BK2];   // 64 KB
    __shared__ unsigned short Bs[2 * BN2 * BK2];   // 64 KB

    const int tid  = threadIdx.x;
    const int wave = tid >> 6, lane = tid & 63;
    const int quad = lane >> 4, l15 = lane & 15;
    const int wm = wave >> 2, wn = wave & 3;       // 2 x 4 wave grid

    // bijective XCD-contiguous swizzle (1376 % 8 == 0): 172 tiles per XCD,
    // nt-fast within a 4-mt-row chunk (A panel L2-resident per XCD).
    int bid = blockIdx.x;
    int swz = (bid & 7) * (MT2 * NT2 / 8) + (bid >> 3);
    int mt = swz / NT2;
    int nt = swz - mt * NT2;
    const int m0 = mt * BM2, n0 = nt * BN2;

    // ---- staging addresses (pre-swizzled global source) ----
    // one STAGE call = 64 rows x 64 k; wave covers rows wave*8 .. +7;
    // lane: row += lane>>3, 16B slot = (lane&7) ^ (lane>>3).
    const int srow  = lane >> 3;
    const int sslot = (lane & 7) ^ srow;
    const unsigned short* gA = A + (size_t)(m0 + wave * 8 + srow) * K_TOTAL + sslot * 8;
    const unsigned short* gB = B + (size_t)(n0 + wave * 8 + srow) * K_TOTAL + sslot * 8;

#define STAGE_A(buf, h, i, kt)                                                     \
    load_lds16(gA + (size_t)((h) * 128 + (i) * 64) * K_TOTAL + (size_t)(kt) * BK2, \
               As + (buf) * (BM2 * BK2) + ((h) * 128 + (i) * 64 + wave * 8) * BK2)
#define STAGE_B(buf, h, i, kt)                                                     \
    load_lds16(gB + (size_t)((h) * 128 + (i) * 64) * K_TOTAL + (size_t)(kt) * BK2, \
               Bs + (buf) * (BN2 * BK2) + ((h) * 128 + (i) * 64 + wave * 8) * BK2)

    // ---- ds_read addresses (swizzled) ----
    const char* AsC = (const char*)As;
    const char* BsC = (const char*)Bs;
    const int rbA  = (wm * 128 + l15) * 128;           // byte row base
    const int rbB  = (wn * 64  + l15) * 128;
    const int swz0 = ( 0 + quad * 16) ^ ((lane & 7) << 4);   // k-slice 0
    const int swz1 = (64 + quad * 16) ^ ((lane & 7) << 4);   // k-slice 1

#define RD_A(buf, fm, SW) \
    (*(const bf16x8*)(AsC + (buf) * (BM2 * BK2 * 2) + rbA + (fm) * 2048 + (SW)))
#define RD_B(buf, fn, SW) \
    (*(const bf16x8*)(BsC + (buf) * (BN2 * BK2 * 2) + rbB + (fn) * 2048 + (SW)))

    f32x4 acc[8][4];
    #pragma unroll
    for (int i = 0; i < 8; ++i)
        #pragma unroll
        for (int j = 0; j < 4; ++j)
            acc[i][j] = (f32x4){0.f, 0.f, 0.f, 0.f};

    // ---- prologue: tile0 fully (8 calls) -> buf0; tile1 A-half0 (2) -> buf1
    STAGE_A(0, 0, 0, 0); STAGE_A(0, 0, 1, 0);
    STAGE_A(0, 1, 0, 0); STAGE_A(0, 1, 1, 0);
    STAGE_B(0, 0, 0, 0); STAGE_B(0, 0, 1, 0);
    STAGE_B(0, 1, 0, 0); STAGE_B(0, 1, 1, 0);
    STAGE_A(1, 0, 0, 1); STAGE_A(1, 0, 1, 1);
    asm volatile("s_waitcnt vmcnt(2)" ::: "memory");   // tile0 resident; tile1-A0 in flight
    __builtin_amdgcn_s_barrier();

    bf16x8 a[4][2], b[4][2];

    for (int t = 0; t < NKT - 1; ++t) {
        const int cur = t & 1, nxt = cur ^ 1;
        const int kn = t + 1;
        const int kp = (t + 2 < NKT) ? (t + 2) : (NKT - 1);  // last iter: dummy into dead buf

        // ---- P0: rd a[0..3], b[0..1]; stage B(t+1) x4 ----
        #pragma unroll
        for (int fm = 0; fm < 4; ++fm) {
            a[fm][0] = RD_A(cur, fm, swz0);
            a[fm][1] = RD_A(cur, fm, swz1);
        }
        #pragma unroll
        for (int fn = 0; fn < 2; ++fn) {
            b[fn][0] = RD_B(cur, fn, swz0);
            b[fn][1] = RD_B(cur, fn, swz1);
        }
        STAGE_B(nxt, 0, 0, kn); STAGE_B(nxt, 0, 1, kn);
        STAGE_B(nxt, 1, 0, kn); STAGE_B(nxt, 1, 1, kn);
        __builtin_amdgcn_s_barrier();
        asm volatile("s_waitcnt lgkmcnt(0)" ::: "memory");
        __builtin_amdgcn_s_setprio(1);
        #pragma unroll
        for (int fm = 0; fm < 4; ++fm)
            #pragma unroll
            for (int fn = 0; fn < 2; ++fn) {
                acc[fm][fn] = __builtin_amdgcn_mfma_f32_16x16x32_bf16(a[fm][0], b[fn][0], acc[fm][fn], 0, 0, 0);
                acc[fm][fn] = __builtin_amdgcn_mfma_f32_16x16x32_bf16(a[fm][1], b[fn][1], acc[fm][fn], 0, 0, 0);
            }
        __builtin_amdgcn_s_setprio(0);
        __builtin_amdgcn_s_barrier();

        // ---- P1: rd b[2..3]; stage A-half1(t+1) x2 ----
        #pragma unroll
        for (int fn = 2; fn < 4; ++fn) {
            b[fn][0] = RD_B(cur, fn, swz0);
            b[fn][1] = RD_B(cur, fn, swz1);
        }
        STAGE_A(nxt, 1, 0, kn); STAGE_A(nxt, 1, 1, kn);
        __builtin_amdgcn_s_barrier();
        asm volatile("s_waitcnt lgkmcnt(0)" ::: "memory");
        __builtin_amdgcn_s_setprio(1);
        #pragma unroll
        for (int fm = 0; fm < 4; ++fm)
            #pragma unroll
            for (int fn = 2; fn < 4; ++fn) {
                acc[fm][fn] = __builtin_amdgcn_mfma_f32_16x16x32_bf16(a[fm][0], b[fn][0], acc[fm][fn], 0, 0, 0);
                acc[fm][fn] = __builtin_amdgcn_mfma_f32_16x16x32_bf16(a[fm][1], b[fn][1], acc[fm][fn], 0, 0, 0);
            }
        __builtin_amdgcn_s_setprio(0);
        __builtin_amdgcn_s_barrier();

        // ---- P2: rd a[4..7] (last reads of buf[cur]) ----
        #pragma unroll
        for (int fm = 0; fm < 4; ++fm) {
            a[fm][0] = RD_A(cur, fm + 4, swz0);
            a[fm][1] = RD_A(cur, fm + 4, swz1);
        }
        __builtin_amdgcn_s_barrier();
        asm volatile("s_waitcnt lgkmcnt(0)" ::: "memory");
        __builtin_amdgcn_s_setprio(1);
        #pragma unroll
        for (int fm = 0; fm < 4; ++fm)
            #pragma unroll
            for (int fn = 0; fn < 2; ++fn) {
                acc[fm + 4][fn] = __builtin_amdgcn_mfma_f32_16x16x32_bf16(a[fm][0], b[fn][0], acc[fm + 4][fn], 0, 0, 0);
                acc[fm + 4][fn] = __builtin_amdgcn_mfma_f32_16x16x32_bf16(a[fm][1], b[fn][1], acc[fm + 4][fn], 0, 0, 0);
            }
        __builtin_amdgcn_s_setprio(0);
        __builtin_amdgcn_s_barrier();
        // after this barrier: every wave's reads of buf[cur] are retired

        // ---- P3: pre-issue A-half0(t+2) into buf[cur]; compute C3 ----
        STAGE_A(cur, 0, 0, kp); STAGE_A(cur, 0, 1, kp);
        __builtin_amdgcn_s_setprio(1);
        #pragma unroll
        for (int fm = 0; fm < 4; ++fm)
            #pragma unroll
            for (int fn = 2; fn < 4; ++fn) {
                acc[fm + 4][fn] = __builtin_amdgcn_mfma_f32_16x16x32_bf16(a[fm][0], b[fn][0], acc[fm + 4][fn], 0, 0, 0);
                acc[fm + 4][fn] = __builtin_amdgcn_mfma_f32_16x16x32_bf16(a[fm][1], b[fn][1], acc[fm + 4][fn], 0, 0, 0);
            }
        __builtin_amdgcn_s_setprio(0);
        // drain tile t+1's 8 loads (oldest); keep t+2's A-half0 (2) in flight
        asm volatile("s_waitcnt vmcnt(2)" ::: "memory");
        __builtin_amdgcn_s_barrier();
    }

    // ---- epilogue: tile NKT-1 from buf1 (resident); drain dummies ----
    asm volatile("s_waitcnt vmcnt(0)" ::: "memory");
    __builtin_amdgcn_s_barrier();
    #pragma unroll
    for (int fm = 0; fm < 4; ++fm) {
        a[fm][0] = RD_A(1, fm, swz0);
        a[fm][1] = RD_A(1, fm, swz1);
    }
    #pragma unroll
    for (int fn = 0; fn < 4; ++fn) {
        b[fn][0] = RD_B(1, fn, swz0);
        b[fn][1] = RD_B(1, fn, swz1);
    }
    #pragma unroll
    for (int fm = 0; fm < 4; ++fm)
        #pragma unroll
        for (int fn = 0; fn < 4; ++fn) {
            acc[fm][fn] = __builtin_amdgcn_mfma_f32_16x16x32_bf16(a[fm][0], b[fn][0], acc[fm][fn], 0, 0, 0);
            acc[fm][fn] = __builtin_amdgcn_mfma_f32_16x16x32_bf16(a[fm][1], b[fn][1], acc[fm][fn], 0, 0, 0);
        }
    #pragma unroll
    for (int fm = 0; fm < 4; ++fm) {
        a[fm][0] = RD_A(1, fm + 4, swz0);
        a[fm][1] = RD_A(1, fm + 4, swz1);
    }
    #pragma unroll
    for (int fm = 0; fm < 4; ++fm)
        #pragma unroll
        for (int fn = 0; fn < 4; ++fn) {
            acc[fm + 4][fn] = __builtin_amdgcn_mfma_f32_16x16x32_bf16(a[fm][0], b[fn][0], acc[fm + 4][fn], 0, 0, 0);
            acc[fm + 4][fn] = __builtin_amdgcn_mfma_f32_16x16x32_bf16(a[fm][1], b[fn][1], acc[fm + 4][fn], 0, 0, 0);
        }

    // ---- C write: col = nb + fn*16 + l15, row = mb + fm*16 + quad*4 + r ----
    const int mb = m0 + wm * 128;
    const int nb = n0 + wn * 64;
    float bv[4];
    #pragma unroll
    for (int fn = 0; fn < 4; ++fn) bv[fn] = bias[nb + fn * 16 + l15];

    #pragma unroll
    for (int fm = 0; fm < 8; ++fm)
        #pragma unroll
        for (int fn = 0; fn < 4; ++fn) {
            const int col = nb + fn * 16 + l15;
            #pragma unroll
            for (int r = 0; r < 4; ++r) {
                const int row = mb + fm * 16 + quad * 4 + r;
                out[(size_t)row * N_TOTAL + col] = acc[fm][fn][r] + bv[fn];
            }
        }
#undef STAGE_A
#undef STAGE_B
#undef RD_A
#undef RD_B
}

// ---------------- R1 fused kernel (fallback if ws too small) ----------------
#define LDS_STRIDE 40

__global__ __launch_bounds__(256)
void int4linear_fused(const float* __restrict__ x,
                      const int*   __restrict__ wp,
                      const float* __restrict__ scale,
                      const float* __restrict__ zp,
                      const float* __restrict__ bias,
                      float*       __restrict__ out)
{
    __shared__ unsigned short As[BM * LDS_STRIDE];
    __shared__ unsigned short Bs[BN * LDS_STRIDE];

    const int t = threadIdx.x;
    int bid = blockIdx.x;
    const int per_group = 8 * NT;
    int grp = bid / per_group;
    int ing = bid - grp * per_group;
    int m0 = (grp * 8 + (ing & 7)) * BM;
    int n0 = (ing >> 3) * BN;

    const int srow  = t >> 1;
    const int shalf = t & 1;

    const float* aptr = x  + (size_t)(m0 + srow) * K_TOTAL + shalf * 16;
    const int*   bptr = wp + (size_t)(n0 + srow) * KP      + shalf * 8;
    const float* sptr = scale + (size_t)(n0 + srow) * NG;
    const float* zptr = zp    + (size_t)(n0 + srow) * NG;

    unsigned short* AsW = &As[srow * LDS_STRIDE + shalf * 16];
    unsigned short* BsW = &Bs[srow * LDS_STRIDE + shalf * 16];

    const int wave = t >> 6;
    const int lane = t & 63;
    const int wm   = wave >> 1;
    const int wn   = wave & 1;
    const int quad = lane >> 4;
    const int l15  = lane & 15;

    const unsigned short* AsR = &As[(wm * 64 + l15) * LDS_STRIDE + quad * 8];
    const unsigned short* BsR = &Bs[(wn * 64 + l15) * LDS_STRIDE + quad * 8];

    f32x4 acc[4][4];
    #pragma unroll
    for (int i = 0; i < 4; ++i)
        #pragma unroll
        for (int j = 0; j < 4; ++j)
            acc[i][j] = (f32x4){0.f, 0.f, 0.f, 0.f};

    for (int kt = 0; kt < K_TOTAL / BK; ++kt) {
        float4 a0 = ((const float4*)aptr)[0];
        float4 a1 = ((const float4*)aptr)[1];
        float4 a2 = ((const float4*)aptr)[2];
        float4 a3 = ((const float4*)aptr)[3];
        int4   b0 = ((const int4*)bptr)[0];
        int4   b1 = ((const int4*)bptr)[1];
        const int g = kt >> 2;
        float s = sptr[g];
        float c = -zptr[g] * s;
        aptr += BK;
        bptr += BK / 2;

        __syncthreads();

        unsigned au0 = pack2_bf16(a0.x, a0.y), au1 = pack2_bf16(a0.z, a0.w);
        unsigned au2 = pack2_bf16(a1.x, a1.y), au3 = pack2_bf16(a1.z, a1.w);
        unsigned au4 = pack2_bf16(a2.x, a2.y), au5 = pack2_bf16(a2.z, a2.w);
        unsigned au6 = pack2_bf16(a3.x, a3.y), au7 = pack2_bf16(a3.z, a3.w);
        ((uint4*)AsW)[0] = make_uint4(au0, au1, au2, au3);
        ((uint4*)AsW)[1] = make_uint4(au4, au5, au6, au7);

        int bv[8] = {b0.x, b0.y, b0.z, b0.w, b1.x, b1.y, b1.z, b1.w};
        unsigned bu[8];
        #pragma unroll
        for (int j = 0; j < 8; ++j) {
            unsigned v = (unsigned)bv[j];
            float fh = (float)((v >> 4) & 15u) * s + c;
            float fl = (float)( v       & 15u) * s + c;
            bu[j] = pack2_bf16(fh, fl);
        }
        ((uint4*)BsW)[0] = make_uint4(bu[0], bu[1], bu[2], bu[3]);
        ((uint4*)BsW)[1] = make_uint4(bu[4], bu[5], bu[6], bu[7]);

        __syncthreads();

        bf16x8 af[4], bf[4];
        #pragma unroll
        for (int i = 0; i < 4; ++i) {
            af[i] = *(const bf16x8*)(AsR + i * 16 * LDS_STRIDE);
            bf[i] = *(const bf16x8*)(BsR + i * 16 * LDS_STRIDE);
        }
        #pragma unroll
        for (int i = 0; i < 4; ++i)
            #pragma unroll
            for (int j = 0; j < 4; ++j)
                acc[i][j] = __builtin_amdgcn_mfma_f32_16x16x32_bf16(
                    af[i], bf[j], acc[i][j], 0, 0, 0);
    }

    const int m_base = m0 + wm * 64;
    const int n_base = n0 + wn * 64;

    float bvec[4];
    #pragma unroll
    for (int j = 0; j < 4; ++j) bvec[j] = bias[n_base + j * 16 + l15];

    #pragma unroll
    for (int i = 0; i < 4; ++i) {
        #pragma unroll
        for (int j = 0; j < 4; ++j) {
            const int col = n_base + j * 16 + l15;
            #pragma unroll
            for (int r = 0; r < 4; ++r) {
                const int row = m_base + i * 16 + quad * 4 + r;
                out[(size_t)row * N_TOTAL + col] = acc[i][j][r] + bvec[j];
            }
        }
    }
}

extern "C" void kernel_launch(void* const* d_in, const int* in_sizes, int n_in,
                              void* d_out, int out_size, void* d_ws, size_t ws_size,
                              hipStream_t stream) {
    const float* x     = (const float*)d_in[0];
    const int*   wpk   = (const int*)  d_in[1];
    const float* scale = (const float*)d_in[2];
    const float* zp    = (const float*)d_in[3];
    const float* bias  = (const float*)d_in[4];
    float* out = (float*)d_out;

    const size_t xb_elems = (size_t)M_TOTAL * K_TOTAL;            // 33.5M
    const size_t wb_elems = (size_t)N_TOTAL * K_TOTAL;            // 45.1M
    const size_t need = (xb_elems + wb_elems) * sizeof(unsigned short); // 157.3 MB

    if (ws_size >= need) {
        unsigned short* xb = (unsigned short*)d_ws;
        unsigned short* wb = xb + xb_elems;

        convert_x<<<dim3((unsigned)(xb_elems / (256 * 8))), 256, 0, stream>>>(x, xb);
        dequant_w<<<dim3((unsigned)((size_t)N_TOTAL * KP / (256 * 4))), 256, 0, stream>>>(
            wpk, scale, zp, wb);
        gemm256<<<dim3(MT2 * NT2), 512, 0, stream>>>(xb, wb, bias, out);
    } else {
        int4linear_fused<<<dim3(MT * NT), 256, 0, stream>>>(x, wpk, scale, zp, bias, out);
    }
}

// Round 3
// 1124.921 us; speedup vs baseline: 1.2435x; 1.0023x over previous
//
#include <hip/hip_runtime.h>
#include <stdint.h>

// Int4Linear: out[M,N] = x[M,K] @ dequant(W)[N,K]^T + bias[N]
// M=8192, N=11008, K=4096.
//
// R5: deepened pipeline. Tile t+2 is staged DURING iteration t (chunk-wise,
// each chunk issued right after the phase where its LDS rows' reads retire:
// A rows 0-63/128-191 after P0, B after P1, A rows 64-127/192-255 after P2).
// Tile t+1 is therefore fully in flight a whole iteration before its drain.
// Both waits are vmcnt(10): P1-end drains A-i1(t) [6 phases old], P3-end
// drains A-i0+B(t+1) [5-6 phases old]. Never 0 in the loop; last 2 iters
// re-stage tile NKT-1 (L2-hot, byte-identical) to keep counts uniform.

#define M_TOTAL 8192
#define N_TOTAL 11008
#define K_TOTAL 4096
#define KP      2048
#define NG      32

// fused-fallback geometry (R1 kernel)
#define BM 128
#define BN 128
#define BK 32
#define MT (M_TOTAL / BM)   // 64
#define NT (N_TOTAL / BN)   // 86

// 256x256 GEMM geometry
#define BM2 256
#define BN2 256
#define BK2 64
#define MT2 (M_TOTAL / BM2)   // 32
#define NT2 (N_TOTAL / BN2)   // 43
#define NKT (K_TOTAL / BK2)   // 64

typedef __bf16 bf16x8 __attribute__((ext_vector_type(8)));
typedef float  f32x4  __attribute__((ext_vector_type(4)));

__device__ __forceinline__ unsigned pack2_bf16(float f0, float f1) {
    unsigned b0 = __float_as_uint(f0);
    unsigned b1 = __float_as_uint(f1);
    return ((b0 + 0x8000u) >> 16) | ((b1 + 0x8000u) & 0xFFFF0000u);
}

// ---------------- pass 1a: x fp32 -> bf16 ----------------
__global__ __launch_bounds__(256)
void convert_x(const float* __restrict__ x, unsigned short* __restrict__ xb)
{
    size_t i = ((size_t)blockIdx.x * 256 + threadIdx.x) * 8;
    float4 a0 = *(const float4*)(x + i);
    float4 a1 = *(const float4*)(x + i + 4);
    uint4 o;
    o.x = pack2_bf16(a0.x, a0.y);
    o.y = pack2_bf16(a0.z, a0.w);
    o.z = pack2_bf16(a1.x, a1.y);
    o.w = pack2_bf16(a1.z, a1.w);
    *(uint4*)(xb + i) = o;
}

// ---------------- pass 1b: W int4 -> bf16 [N,K] row-major ----------------
__global__ __launch_bounds__(256)
void dequant_w(const int* __restrict__ wp, const float* __restrict__ scale,
               const float* __restrict__ zp, unsigned short* __restrict__ wb)
{
    size_t tid = (size_t)blockIdx.x * 256 + threadIdx.x;
    size_t pi = tid * 4;
    int row = (int)(pi >> 11);
    int p0  = (int)(pi & (KP - 1));
    int g   = p0 >> 6;
    float s = scale[row * NG + g];
    float c = -zp[row * NG + g] * s;
    int4 v = *(const int4*)(wp + pi);
    int bv[4] = {v.x, v.y, v.z, v.w};
    unsigned ou[4];
    #pragma unroll
    for (int j = 0; j < 4; ++j) {
        unsigned u = (unsigned)bv[j];
        float fh = (float)((u >> 4) & 15u) * s + c;
        float fl = (float)( u       & 15u) * s + c;
        ou[j] = pack2_bf16(fh, fl);
    }
    *(uint4*)(wb + 2 * pi) = make_uint4(ou[0], ou[1], ou[2], ou[3]);
}

// ---------------- global -> LDS direct (width 16) ----------------
__device__ __forceinline__ void load_lds16(const void* g, void* l) {
    __builtin_amdgcn_global_load_lds(
        (const __attribute__((address_space(1))) unsigned int*)(uintptr_t)g,
        (__attribute__((address_space(3))) unsigned int*)(uintptr_t)l,
        16, 0, 0);
}

// ---------------- pass 2: 256x256 4-phase bf16 GEMM, 2-tile-deep ----------
// LDS tile: [256 rows][64 k] bf16, 128 B/row. 16B slot c of row r holds
// global slot c ^ (r&7) (pre-swizzled global source, linear LDS dest;
// ds_read applies the same XOR). ds_read_b128 conflict: 16-way -> 2-way.
//
// Chunk read-retirement (by phase, all waves):
//   A rows   0- 63 (h0,i0): P0     A rows  64-127 (h0,i1): P2
//   A rows 128-191 (h1,i0): P0     A rows 192-255 (h1,i1): P2
//   B rows: fn0-1 at P0, fn2-3 at P1 -> all B retired at P1-end.
// Stage schedule for tile t+2 -> buf[cur]: P1: A(h,0)x2; P2: Bx4; P3: A(h,1)x2.

__global__ __launch_bounds__(512, 2)
void gemm256(const unsigned short* __restrict__ A,   // [M,K] bf16
             const unsigned short* __restrict__ B,   // [N,K] bf16
             const float* __restrict__ bias,
             float* __restrict__ out)
{
    __shared__ unsigned short As[2 * BM2 * BK2];   // 64 KB
    __shared__ unsigned short Bs[2 * BN2 * BK2];   // 64 KB

    const int tid  = threadIdx.x;
    const int wave = tid >> 6, lane = tid & 63;
    const int quad = lane >> 4, l15 = lane & 15;
    const int wm = wave >> 2, wn = wave & 3;       // 2 x 4 wave grid

    // bijective XCD-contiguous swizzle (1376 % 8 == 0): 172 tiles per XCD,
    // nt-fast within a 4-mt-row chunk (A panel L2-resident per XCD).
    int bid = blockIdx.x;
    int swz = (bid & 7) * (MT2 * NT2 / 8) + (bid >> 3);
    int mt = swz / NT2;
    int nt = swz - mt * NT2;
    const int m0 = mt * BM2, n0 = nt * BN2;

    // ---- staging addresses (pre-swizzled global source) ----
    // one STAGE call = 64 rows x 64 k; wave covers rows wave*8 .. +7;
    // lane: row += lane>>3, 16B slot = (lane&7) ^ (lane>>3).
    const int srow  = lane >> 3;
    const int sslot = (lane & 7) ^ srow;
    const unsigned short* gA = A + (size_t)(m0 + wave * 8 + srow) * K_TOTAL + sslot * 8;
    const unsigned short* gB = B + (size_t)(n0 + wave * 8 + srow) * K_TOTAL + sslot * 8;

#define STAGE_A(buf, h, i, kt)                                                     \
    load_lds16(gA + (size_t)((h) * 128 + (i) * 64) * K_TOTAL + (size_t)(kt) * BK2, \
               As + (buf) * (BM2 * BK2) + ((h) * 128 + (i) * 64 + wave * 8) * BK2)
#define STAGE_B(buf, h, i, kt)                                                     \
    load_lds16(gB + (size_t)((h) * 128 + (i) * 64) * K_TOTAL + (size_t)(kt) * BK2, \
               Bs + (buf) * (BN2 * BK2) + ((h) * 128 + (i) * 64 + wave * 8) * BK2)

    // ---- ds_read addresses (swizzled) ----
    const char* AsC = (const char*)As;
    const char* BsC = (const char*)Bs;
    const int rbA  = (wm * 128 + l15) * 128;           // byte row base
    const int rbB  = (wn * 64  + l15) * 128;
    const int swz0 = ( 0 + quad * 16) ^ ((lane & 7) << 4);   // k-slice 0
    const int swz1 = (64 + quad * 16) ^ ((lane & 7) << 4);   // k-slice 1

#define RD_A(buf, fm, SW) \
    (*(const bf16x8*)(AsC + (buf) * (BM2 * BK2 * 2) + rbA + (fm) * 2048 + (SW)))
#define RD_B(buf, fn, SW) \
    (*(const bf16x8*)(BsC + (buf) * (BN2 * BK2 * 2) + rbB + (fn) * 2048 + (SW)))

    f32x4 acc[8][4];
    #pragma unroll
    for (int i = 0; i < 8; ++i)
        #pragma unroll
        for (int j = 0; j < 4; ++j)
            acc[i][j] = (f32x4){0.f, 0.f, 0.f, 0.f};

    // ---- prologue: tile0 -> buf0, tile1 -> buf1 (16 loads in flight) ----
    // order per tile: A(0,0) A(1,0) Bx4 A(0,1) A(1,1)
    STAGE_A(0, 0, 0, 0); STAGE_A(0, 1, 0, 0);
    STAGE_B(0, 0, 0, 0); STAGE_B(0, 0, 1, 0);
    STAGE_B(0, 1, 0, 0); STAGE_B(0, 1, 1, 0);
    STAGE_A(0, 0, 1, 0); STAGE_A(0, 1, 1, 0);
    STAGE_A(1, 0, 0, 1); STAGE_A(1, 1, 0, 1);
    STAGE_B(1, 0, 0, 1); STAGE_B(1, 0, 1, 1);
    STAGE_B(1, 1, 0, 1); STAGE_B(1, 1, 1, 1);
    STAGE_A(1, 0, 1, 1); STAGE_A(1, 1, 1, 1);
    asm volatile("s_waitcnt vmcnt(10)" ::: "memory");  // tile0 A-i0 + B resident
    __builtin_amdgcn_s_barrier();

    bf16x8 a[4][2], b[4][2];

    for (int t = 0; t < NKT; ++t) {
        const int cur = t & 1;
        const int k2 = (t + 2 < NKT) ? (t + 2) : (NKT - 1);  // clamped dummy (L2-hot)

        // ---- P0: rd a[0..3], b[0..1] of tile t ----
        #pragma unroll
        for (int fm = 0; fm < 4; ++fm) {
            a[fm][0] = RD_A(cur, fm, swz0);
            a[fm][1] = RD_A(cur, fm, swz1);
        }
        #pragma unroll
        for (int fn = 0; fn < 2; ++fn) {
            b[fn][0] = RD_B(cur, fn, swz0);
            b[fn][1] = RD_B(cur, fn, swz1);
        }
        __builtin_amdgcn_s_barrier();
        asm volatile("s_waitcnt lgkmcnt(0)" ::: "memory");
        __builtin_amdgcn_s_setprio(1);
        #pragma unroll
        for (int fm = 0; fm < 4; ++fm)
            #pragma unroll
            for (int fn = 0; fn < 2; ++fn) {
                acc[fm][fn] = __builtin_amdgcn_mfma_f32_16x16x32_bf16(a[fm][0], b[fn][0], acc[fm][fn], 0, 0, 0);
                acc[fm][fn] = __builtin_amdgcn_mfma_f32_16x16x32_bf16(a[fm][1], b[fn][1], acc[fm][fn], 0, 0, 0);
            }
        __builtin_amdgcn_s_setprio(0);
        __builtin_amdgcn_s_barrier();

        // ---- P1: stage A(h,0)(t+2); rd b[2..3]; drain A-i1(t) ----
        STAGE_A(cur, 0, 0, k2); STAGE_A(cur, 1, 0, k2);
        #pragma unroll
        for (int fn = 2; fn < 4; ++fn) {
            b[fn][0] = RD_B(cur, fn, swz0);
            b[fn][1] = RD_B(cur, fn, swz1);
        }
        asm volatile("s_waitcnt vmcnt(10)" ::: "memory");  // A-i1(t) resident for P2
        __builtin_amdgcn_s_barrier();
        asm volatile("s_waitcnt lgkmcnt(0)" ::: "memory");
        __builtin_amdgcn_s_setprio(1);
        #pragma unroll
        for (int fm = 0; fm < 4; ++fm)
            #pragma unroll
            for (int fn = 2; fn < 4; ++fn) {
                acc[fm][fn] = __builtin_amdgcn_mfma_f32_16x16x32_bf16(a[fm][0], b[fn][0], acc[fm][fn], 0, 0, 0);
                acc[fm][fn] = __builtin_amdgcn_mfma_f32_16x16x32_bf16(a[fm][1], b[fn][1], acc[fm][fn], 0, 0, 0);
            }
        __builtin_amdgcn_s_setprio(0);
        __builtin_amdgcn_s_barrier();

        // ---- P2: stage B(t+2) x4; rd a[4..7] ----
        STAGE_B(cur, 0, 0, k2); STAGE_B(cur, 0, 1, k2);
        STAGE_B(cur, 1, 0, k2); STAGE_B(cur, 1, 1, k2);
        #pragma unroll
        for (int fm = 0; fm < 4; ++fm) {
            a[fm][0] = RD_A(cur, fm + 4, swz0);
            a[fm][1] = RD_A(cur, fm + 4, swz1);
        }
        __builtin_amdgcn_s_barrier();
        asm volatile("s_waitcnt lgkmcnt(0)" ::: "memory");
        __builtin_amdgcn_s_setprio(1);
        #pragma unroll
        for (int fm = 0; fm < 4; ++fm)
            #pragma unroll
            for (int fn = 0; fn < 2; ++fn) {
                acc[fm + 4][fn] = __builtin_amdgcn_mfma_f32_16x16x32_bf16(a[fm][0], b[fn][0], acc[fm + 4][fn], 0, 0, 0);
                acc[fm + 4][fn] = __builtin_amdgcn_mfma_f32_16x16x32_bf16(a[fm][1], b[fn][1], acc[fm + 4][fn], 0, 0, 0);
            }
        __builtin_amdgcn_s_setprio(0);
        __builtin_amdgcn_s_barrier();

        // ---- P3: stage A(h,1)(t+2); compute C3; drain A-i0+B(t+1) ----
        STAGE_A(cur, 0, 1, k2); STAGE_A(cur, 1, 1, k2);
        __builtin_amdgcn_s_setprio(1);
        #pragma unroll
        for (int fm = 0; fm < 4; ++fm)
            #pragma unroll
            for (int fn = 2; fn < 4; ++fn) {
                acc[fm + 4][fn] = __builtin_amdgcn_mfma_f32_16x16x32_bf16(a[fm][0], b[fn][0], acc[fm + 4][fn], 0, 0, 0);
                acc[fm + 4][fn] = __builtin_amdgcn_mfma_f32_16x16x32_bf16(a[fm][1], b[fn][1], acc[fm + 4][fn], 0, 0, 0);
            }
        __builtin_amdgcn_s_setprio(0);
        asm volatile("s_waitcnt vmcnt(10)" ::: "memory");  // A-i0+B(t+1) resident for next P0
        __builtin_amdgcn_s_barrier();
    }

    asm volatile("s_waitcnt vmcnt(0)" ::: "memory");   // drain dummy stages

    // ---- C write: col = nb + fn*16 + l15, row = mb + fm*16 + quad*4 + r ----
    const int mb = m0 + wm * 128;
    const int nb = n0 + wn * 64;
    float bv[4];
    #pragma unroll
    for (int fn = 0; fn < 4; ++fn) bv[fn] = bias[nb + fn * 16 + l15];

    #pragma unroll
    for (int fm = 0; fm < 8; ++fm)
        #pragma unroll
        for (int fn = 0; fn < 4; ++fn) {
            const int col = nb + fn * 16 + l15;
            #pragma unroll
            for (int r = 0; r < 4; ++r) {
                const int row = mb + fm * 16 + quad * 4 + r;
                out[(size_t)row * N_TOTAL + col] = acc[fm][fn][r] + bv[fn];
            }
        }
#undef STAGE_A
#undef STAGE_B
#undef RD_A
#undef RD_B
}

// ---------------- R1 fused kernel (fallback if ws too small) ----------------
#define LDS_STRIDE 40

__global__ __launch_bounds__(256)
void int4linear_fused(const float* __restrict__ x,
                      const int*   __restrict__ wp,
                      const float* __restrict__ scale,
                      const float* __restrict__ zp,
                      const float* __restrict__ bias,
                      float*       __restrict__ out)
{
    __shared__ unsigned short As[BM * LDS_STRIDE];
    __shared__ unsigned short Bs[BN * LDS_STRIDE];

    const int t = threadIdx.x;
    int bid = blockIdx.x;
    const int per_group = 8 * NT;
    int grp = bid / per_group;
    int ing = bid - grp * per_group;
    int m0 = (grp * 8 + (ing & 7)) * BM;
    int n0 = (ing >> 3) * BN;

    const int srow  = t >> 1;
    const int shalf = t & 1;

    const float* aptr = x  + (size_t)(m0 + srow) * K_TOTAL + shalf * 16;
    const int*   bptr = wp + (size_t)(n0 + srow) * KP      + shalf * 8;
    const float* sptr = scale + (size_t)(n0 + srow) * NG;
    const float* zptr = zp    + (size_t)(n0 + srow) * NG;

    unsigned short* AsW = &As[srow * LDS_STRIDE + shalf * 16];
    unsigned short* BsW = &Bs[srow * LDS_STRIDE + shalf * 16];

    const int wave = t >> 6;
    const int lane = t & 63;
    const int wm   = wave >> 1;
    const int wn   = wave & 1;
    const int quad = lane >> 4;
    const int l15  = lane & 15;

    const unsigned short* AsR = &As[(wm * 64 + l15) * LDS_STRIDE + quad * 8];
    const unsigned short* BsR = &Bs[(wn * 64 + l15) * LDS_STRIDE + quad * 8];

    f32x4 acc[4][4];
    #pragma unroll
    for (int i = 0; i < 4; ++i)
        #pragma unroll
        for (int j = 0; j < 4; ++j)
            acc[i][j] = (f32x4){0.f, 0.f, 0.f, 0.f};

    for (int kt = 0; kt < K_TOTAL / BK; ++kt) {
        float4 a0 = ((const float4*)aptr)[0];
        float4 a1 = ((const float4*)aptr)[1];
        float4 a2 = ((const float4*)aptr)[2];
        float4 a3 = ((const float4*)aptr)[3];
        int4   b0 = ((const int4*)bptr)[0];
        int4   b1 = ((const int4*)bptr)[1];
        const int g = kt >> 2;
        float s = sptr[g];
        float c = -zptr[g] * s;
        aptr += BK;
        bptr += BK / 2;

        __syncthreads();

        unsigned au0 = pack2_bf16(a0.x, a0.y), au1 = pack2_bf16(a0.z, a0.w);
        unsigned au2 = pack2_bf16(a1.x, a1.y), au3 = pack2_bf16(a1.z, a1.w);
        unsigned au4 = pack2_bf16(a2.x, a2.y), au5 = pack2_bf16(a2.z, a2.w);
        unsigned au6 = pack2_bf16(a3.x, a3.y), au7 = pack2_bf16(a3.z, a3.w);
        ((uint4*)AsW)[0] = make_uint4(au0, au1, au2, au3);
        ((uint4*)AsW)[1] = make_uint4(au4, au5, au6, au7);

        int bv[8] = {b0.x, b0.y, b0.z, b0.w, b1.x, b1.y, b1.z, b1.w};
        unsigned bu[8];
        #pragma unroll
        for (int j = 0; j < 8; ++j) {
            unsigned v = (unsigned)bv[j];
            float fh = (float)((v >> 4) & 15u) * s + c;
            float fl = (float)( v       & 15u) * s + c;
            bu[j] = pack2_bf16(fh, fl);
        }
        ((uint4*)BsW)[0] = make_uint4(bu[0], bu[1], bu[2], bu[3]);
        ((uint4*)BsW)[1] = make_uint4(bu[4], bu[5], bu[6], bu[7]);

        __syncthreads();

        bf16x8 af[4], bf[4];
        #pragma unroll
        for (int i = 0; i < 4; ++i) {
            af[i] = *(const bf16x8*)(AsR + i * 16 * LDS_STRIDE);
            bf[i] = *(const bf16x8*)(BsR + i * 16 * LDS_STRIDE);
        }
        #pragma unroll
        for (int i = 0; i < 4; ++i)
            #pragma unroll
            for (int j = 0; j < 4; ++j)
                acc[i][j] = __builtin_amdgcn_mfma_f32_16x16x32_bf16(
                    af[i], bf[j], acc[i][j], 0, 0, 0);
    }

    const int m_base = m0 + wm * 64;
    const int n_base = n0 + wn * 64;

    float bvec[4];
    #pragma unroll
    for (int j = 0; j < 4; ++j) bvec[j] = bias[n_base + j * 16 + l15];

    #pragma unroll
    for (int i = 0; i < 4; ++i) {
        #pragma unroll
        for (int j = 0; j < 4; ++j) {
            const int col = n_base + j * 16 + l15;
            #pragma unroll
            for (int r = 0; r < 4; ++r) {
                const int row = m_base + i * 16 + quad * 4 + r;
                out[(size_t)row * N_TOTAL + col] = acc[i][j][r] + bvec[j];
            }
        }
    }
}

extern "C" void kernel_launch(void* const* d_in, const int* in_sizes, int n_in,
                              void* d_out, int out_size, void* d_ws, size_t ws_size,
                              hipStream_t stream) {
    const float* x     = (const float*)d_in[0];
    const int*   wpk   = (const int*)  d_in[1];
    const float* scale = (const float*)d_in[2];
    const float* zp    = (const float*)d_in[3];
    const float* bias  = (const float*)d_in[4];
    float* out = (float*)d_out;

    const size_t xb_elems = (size_t)M_TOTAL * K_TOTAL;            // 33.5M
    const size_t wb_elems = (size_t)N_TOTAL * K_TOTAL;            // 45.1M
    const size_t need = (xb_elems + wb_elems) * sizeof(unsigned short); // 157.3 MB

    if (ws_size >= need) {
        unsigned short* xb = (unsigned short*)d_ws;
        unsigned short* wb = xb + xb_elems;

        convert_x<<<dim3((unsigned)(xb_elems / (256 * 8))), 256, 0, stream>>>(x, xb);
        dequant_w<<<dim3((unsigned)((size_t)N_TOTAL * KP / (256 * 4))), 256, 0, stream>>>(
            wpk, scale, zp, wb);
        gemm256<<<dim3(MT2 * NT2), 512, 0, stream>>>(xb, wb, bias, out);
    } else {
        int4linear_fused<<<dim3(MT * NT), 256, 0, stream>>>(x, wpk, scale, zp, bias, out);
    }
}